// Round 6
// baseline (306.318 us; speedup 1.0000x reference)
//
#include <hip/hip_runtime.h>
#include <cstdint>

typedef __attribute__((ext_vector_type(8))) short short8;
typedef __attribute__((ext_vector_type(4))) float f32x4;

constexpr int SEQ   = 2048;
constexpr int INSZ  = 256;   // K
constexpr int OUTSZ = 256;

__device__ __forceinline__ ushort f2bf(float f) {
  union { float f; uint32_t u; } v; v.f = f;
  uint32_t u = v.u;
  return (ushort)((u + 0x7FFFu + ((u >> 16) & 1u)) >> 16);  // RNE
}
__device__ __forceinline__ uint32_t pk2(float a, float b) {
  return (uint32_t)f2bf(a) | ((uint32_t)f2bf(b) << 16);
}

// ---------------------------------------------------------------------------
// Kernel 1: W_b = U[idx[b]] @ V, bf16, stored in MFMA B-fragment order:
//   ushort index = b*65536 + k5*8192 + nb*512 + lane*8 + j
// where k5 = k>>5, nb = o>>4, lane = (o&15) + ((k>>3)&3)*16, j = k&7.
// A wave's B fragment (16x32 subtile) is ONE coalesced 1KB load.
// ---------------------------------------------------------------------------
__global__ __launch_bounds__(256) void synth_w(
    const float* __restrict__ U, const float* __restrict__ V,
    const int* __restrict__ idx, ushort* __restrict__ wsW)
{
  const int b   = blockIdx.y;
  const int kb  = blockIdx.x;     // 0..3 -> local k window [kb*64, kb*64+64)
  const int tid = threadIdx.x;
  const int ch  = idx[b];
  const float u0 = U[ch*4+0], u1 = U[ch*4+1], u2 = U[ch*4+2], u3 = U[ch*4+3];

  __shared__ ushort tile[64][260];   // [k_local][o], padded to spread banks

  const int o4    = (tid & 63) * 4;
  const int kbase = (tid >> 6) * 16;
  for (int kk = 0; kk < 16; ++kk) {
    const int k  = kbase + kk;
    const int gk = kb*64 + k;
    const float* vp = V + (size_t)gk*OUTSZ + o4;
    float4 a = *(const float4*)(vp);
    float4 c = *(const float4*)(vp + 65536);
    float4 d = *(const float4*)(vp + 131072);
    float4 e = *(const float4*)(vp + 196608);
    ushort4 pkv;
    pkv.x = f2bf(u0*a.x + u1*c.x + u2*d.x + u3*e.x);
    pkv.y = f2bf(u0*a.y + u1*c.y + u2*d.y + u3*e.y);
    pkv.z = f2bf(u0*a.z + u1*c.z + u2*d.z + u3*e.z);
    pkv.w = f2bf(u0*a.w + u1*c.w + u2*d.w + u3*e.w);
    *(ushort4*)(&tile[k][o4]) = pkv;
  }
  __syncthreads();

  for (int s = 0; s < 8; ++s) {
    const int c      = s*256 + tid;
    const int kshalf = c >> 10;
    const int nb     = (c >> 6) & 15;
    const int lane   = c & 63;
    const int o      = nb*16 + (lane & 15);
    const int k0     = kshalf*32 + (lane >> 4)*8;
    uint4 pkv;
    pkv.x = (uint32_t)tile[k0+0][o] | ((uint32_t)tile[k0+1][o] << 16);
    pkv.y = (uint32_t)tile[k0+2][o] | ((uint32_t)tile[k0+3][o] << 16);
    pkv.z = (uint32_t)tile[k0+4][o] | ((uint32_t)tile[k0+5][o] << 16);
    pkv.w = (uint32_t)tile[k0+6][o] | ((uint32_t)tile[k0+7][o] << 16);
    uint4* dst = (uint4*)(wsW + (size_t)b*65536 + (size_t)(2*kb + kshalf)*8192
                              + nb*512 + lane*8);
    *dst = pkv;
  }
}

// ---------------------------------------------------------------------------
// Kernel 2: out[b, n0:n0+64, :] = x[b, n0:n0+64, :] @ W_b + bias[idx[b]]
// Duty-cycle fix: ALL 64KB of x-reads issue up-front (two 32-row sub-tiles;
// S1 held in regs as bf16 through compute(S0), ds-written during it).
// Direct scattered stores (no LDS bounce). 2 barriers/block.
// ---------------------------------------------------------------------------
__global__ __launch_bounds__(256, 4) void lr_gemm(
    const float* __restrict__ x, const int* __restrict__ idx,
    const float* __restrict__ bias, const ushort* __restrict__ wsW,
    float* __restrict__ out)
{
  __shared__ ushort ldsA[2][32*256];   // 16KB each, XOR-swizzled rows

  // XCD-aware swizzle (8192 = 8*1024): a batch's 32 blocks stay on one XCD
  const int wg  = blockIdx.x;
  const int swz = (wg & 7) * 1024 + (wg >> 3);
  const int b   = swz >> 5;
  const int n0  = (swz & 31) * 64;

  const int tid  = threadIdx.x;
  const int lane = tid & 63;
  const int wave = tid >> 6;      // owns cols [wave*64, wave*64+64)
  const int hi16 = lane >> 4;
  const int lo16 = lane & 15;

  const float*  xb  = x + ((size_t)b*SEQ + n0)*INSZ;
  const ushort* wbp = wsW + (size_t)b*65536 + wave*2048 + lane*8;

  const int row = tid >> 5;       // 0..7 base row (per-it step 8)
  const int c8  = tid & 31;       // 8-float chunk in row

  // ---- issue ALL x reads for both sub-tiles up-front (deep VMEM queue)
  float4 s0[4][2], s1[4][2];
  #pragma unroll
  for (int it = 0; it < 4; ++it) {
    const float* p = xb + (size_t)(it*8 + row)*INSZ + c8*8;
    s0[it][0] = *(const float4*)p;
    s0[it][1] = *(const float4*)(p + 4);
  }
  #pragma unroll
  for (int it = 0; it < 4; ++it) {
    const float* p = xb + (size_t)(32 + it*8 + row)*INSZ + c8*8;
    s1[it][0] = *(const float4*)p;
    s1[it][1] = *(const float4*)(p + 4);
  }
  // B prologue
  short8 bcur[4], bnxt[4];
  #pragma unroll
  for (int n = 0; n < 4; ++n)
    bcur[n] = *(const short8*)(wbp + n*512);

  // ---- convert + ds_write S0
  const int wswz = ((c8*16) ^ ((row & 7) << 4));   // row&7 == (it*8+row)&7
  #pragma unroll
  for (int it = 0; it < 4; ++it) {
    uint4 pkv;
    pkv.x = pk2(s0[it][0].x, s0[it][0].y); pkv.y = pk2(s0[it][0].z, s0[it][0].w);
    pkv.z = pk2(s0[it][1].x, s0[it][1].y); pkv.w = pk2(s0[it][1].z, s0[it][1].w);
    *(uint4*)((char*)ldsA[0] + (it*8 + row)*512 + wswz) = pkv;
  }
  // ---- convert S1 to packed bf16 regs (frees 32 f32 VGPRs -> 16)
  uint4 s1p[4];
  #pragma unroll
  for (int it = 0; it < 4; ++it) {
    s1p[it].x = pk2(s1[it][0].x, s1[it][0].y); s1p[it].y = pk2(s1[it][0].z, s1[it][0].w);
    s1p[it].z = pk2(s1[it][1].x, s1[it][1].y); s1p[it].w = pk2(s1[it][1].z, s1[it][1].w);
  }
  __syncthreads();   // S0 visible

  const int sx = (lo16 & 7) << 4;
  const char* aB0 = (const char*)ldsA[0] + lo16*512;
  const char* aB1 = (const char*)ldsA[1] + lo16*512;

  f32x4 acc[2][4] = {};
  #pragma unroll
  for (int k5 = 0; k5 < 8; ++k5) {
    if (k5 == 0) {   // ds_write S1 under compute(S0); read after barrier2 only
      #pragma unroll
      for (int it = 0; it < 4; ++it)
        *(uint4*)((char*)ldsA[1] + (it*8 + row)*512 + wswz) = s1p[it];
    }
    if (k5 < 7) {
      #pragma unroll
      for (int n = 0; n < 4; ++n)
        bnxt[n] = *(const short8*)(wbp + (size_t)(k5+1)*8192 + n*512);
    }
    short8 af[2];
    #pragma unroll
    for (int m = 0; m < 2; ++m)
      af[m] = *(const short8*)(aB0 + m*8192 + ((k5*64 + hi16*16) ^ sx));
    #pragma unroll
    for (int m = 0; m < 2; ++m)
      #pragma unroll
      for (int n = 0; n < 4; ++n)
        acc[m][n] = __builtin_amdgcn_mfma_f32_16x16x32_bf16(af[m], bcur[n], acc[m][n], 0, 0, 0);
    #pragma unroll
    for (int n = 0; n < 4; ++n) bcur[n] = bnxt[n];
  }

  __syncthreads();   // S1 visible (all waves' ds_writes done long ago)

  // ---- store S0 (after barrier: avoids vmcnt(0) store-drain at the barrier)
  const int ch = idx[b];
  const float* bb = bias + (size_t)ch*OUTSZ;
  float bv[4];
  #pragma unroll
  for (int n = 0; n < 4; ++n) bv[n] = bb[wave*64 + n*16 + lo16];

  float* outb = out + ((size_t)b*SEQ + n0)*OUTSZ;
  #pragma unroll
  for (int m = 0; m < 2; ++m) {
    const int r = m*16 + hi16*4;
    #pragma unroll
    for (int n = 0; n < 4; ++n) {
      const int col = wave*64 + n*16 + lo16;
      #pragma unroll
      for (int j = 0; j < 4; ++j)
        outb[(size_t)(r + j)*OUTSZ + col] = acc[m][n][j] + bv[n];
    }
  }

  // ---- compute S1
  f32x4 acc1[2][4] = {};
  #pragma unroll
  for (int n = 0; n < 4; ++n)
    bcur[n] = *(const short8*)(wbp + n*512);
  #pragma unroll
  for (int k5 = 0; k5 < 8; ++k5) {
    if (k5 < 7) {
      #pragma unroll
      for (int n = 0; n < 4; ++n)
        bnxt[n] = *(const short8*)(wbp + (size_t)(k5+1)*8192 + n*512);
    }
    short8 af[2];
    #pragma unroll
    for (int m = 0; m < 2; ++m)
      af[m] = *(const short8*)(aB1 + m*8192 + ((k5*64 + hi16*16) ^ sx));
    #pragma unroll
    for (int m = 0; m < 2; ++m)
      #pragma unroll
      for (int n = 0; n < 4; ++n)
        acc1[m][n] = __builtin_amdgcn_mfma_f32_16x16x32_bf16(af[m], bcur[n], acc1[m][n], 0, 0, 0);
    #pragma unroll
    for (int n = 0; n < 4; ++n) bcur[n] = bnxt[n];
  }

  // ---- store S1
  #pragma unroll
  for (int m = 0; m < 2; ++m) {
    const int r = 32 + m*16 + hi16*4;
    #pragma unroll
    for (int n = 0; n < 4; ++n) {
      const int col = wave*64 + n*16 + lo16;
      #pragma unroll
      for (int j = 0; j < 4; ++j)
        outb[(size_t)(r + j)*OUTSZ + col] = acc1[m][n][j] + bv[n];
    }
  }
}

extern "C" void kernel_launch(void* const* d_in, const int* in_sizes, int n_in,
                              void* d_out, int out_size, void* d_ws, size_t ws_size,
                              hipStream_t stream) {
  const float* x    = (const float*)d_in[0];
  const int*   idx  = (const int*)d_in[1];
  const float* U    = (const float*)d_in[2];
  const float* V    = (const float*)d_in[3];
  const float* bias = (const float*)d_in[4];
  float* out  = (float*)d_out;
  ushort* wsW = (ushort*)d_ws;     // 256*65536*2 = 32 MiB

  synth_w<<<dim3(4, 256), 256, 0, stream>>>(U, V, idx, wsW);
  lr_gemm<<<8192, 256, 0, stream>>>(x, idx, bias, wsW, out);
}